// Round 8
// baseline (234.936 us; speedup 1.0000x reference)
//
#include <hip/hip_runtime.h>
#include <hip/hip_bf16.h>

// Problem constants
#define BB 2
#define SS 2048
#define HH 1024
#define NHH 16
#define HDD 64
#define MM (BB*SS)        // 4096
#define QKV_N (3*HH)      // 3072

typedef _Float16 f16x8 __attribute__((ext_vector_type(8)));
typedef _Float16 f16x4 __attribute__((ext_vector_type(4)));
typedef float f32x4 __attribute__((ext_vector_type(4)));

#define MFMA16(a,b,c) __builtin_amdgcn_mfma_f32_16x16x32_f16((a),(b),(c),0,0,0)

// async global->LDS 16B per lane; LDS dest = wave-uniform base + lane*16
__device__ __forceinline__ void gl2lds16(const _Float16* g, _Float16* l) {
    __builtin_amdgcn_global_load_lds(
        (const __attribute__((address_space(1))) void*)g,
        (__attribute__((address_space(3))) void*)l, 16, 0, 0);
}

// ---------------- cast fp32 -> fp16, vectorized ----------------
__global__ void cast4_kernel(const float* __restrict__ x, _Float16* __restrict__ y, int n4) {
    int i = blockIdx.x * blockDim.x + threadIdx.x;
    if (i < n4) {
        float4 v = ((const float4*)x)[i];
        f16x4 h = {(_Float16)v.x, (_Float16)v.y, (_Float16)v.z, (_Float16)v.w};
        ((f16x4*)y)[i] = h;
    }
}

// ---------------- transpose-cast W[k][n] fp32 -> Wt[n][k] fp16, 64x64 tiles -------------
// grid (16,16,4), block 256. z: 0..2 -> WqkvT slices, 3 -> WoT.
__global__ __launch_bounds__(256) void transpose_kernel(
    const float* __restrict__ W0, const float* __restrict__ W1,
    const float* __restrict__ W2, const float* __restrict__ W3,
    _Float16* __restrict__ WqkvT, _Float16* __restrict__ WoT)
{
    __shared__ float t[64][65];
    int z = blockIdx.z;
    const float* src = (z == 0) ? W0 : (z == 1) ? W1 : (z == 2) ? W2 : W3;
    _Float16* dst = (z < 3) ? (WqkvT + (size_t)z * HH * HH) : WoT;
    int k0 = blockIdx.y * 64, n0 = blockIdx.x * 64;
    int tid = threadIdx.x;

#pragma unroll
    for (int p = 0; p < 4; ++p) {
        int row = p * 16 + (tid >> 4);
        int col4 = (tid & 15) * 4;
        float4 v = *(const float4*)&src[(size_t)(k0 + row) * HH + n0 + col4];
        t[row][col4 + 0] = v.x; t[row][col4 + 1] = v.y;
        t[row][col4 + 2] = v.z; t[row][col4 + 3] = v.w;
    }
    __syncthreads();
#pragma unroll
    for (int p = 0; p < 2; ++p) {
        int nc = p * 32 + (tid >> 3);
        int ch = tid & 7;
        f16x8 o;
#pragma unroll
        for (int j = 0; j < 8; ++j) o[j] = (_Float16)t[ch * 8 + j][nc];
        *(f16x8*)&dst[(size_t)(n0 + nc) * HH + k0 + ch * 8] = o;
    }
}

// ---------------- MFMA GEMM 128x128 tile, pipelined dbuf staging ----------------
template<int MODE>
__global__ __launch_bounds__(256) void gemm128_kernel(
    const _Float16* __restrict__ A, const _Float16* __restrict__ Bt,
    const float* __restrict__ bias0, const float* __restrict__ bias1, const float* __restrict__ bias2,
    _Float16* __restrict__ Qh, _Float16* __restrict__ Kh, _Float16* __restrict__ Vt,
    float* __restrict__ Out)
{
    const int K = HH;
    const int NT = K / 32;
    __shared__ _Float16 smem[16896];          // 33792 B: dbuf (32 KB) U epilogue tile 128x132

    int row0 = blockIdx.y * 128, n0 = blockIdx.x * 128;
    int tid = threadIdx.x;
    int w = tid >> 6, l = tid & 63, m16 = l & 15, quad = l >> 4;
    int wm = w >> 1, wn = w & 1;

    int srow = w * 32 + (l >> 2);
    int sch = (l & 3) ^ ((l >> 2) & 3) ^ ((l >> 4) & 3);
    const _Float16* aptr = A + (size_t)(row0 + srow) * K + sch * 8;
    const _Float16* bptr = Bt + (size_t)(n0 + srow) * K + sch * 8;

    int gsw = (m16 & 3) ^ ((m16 >> 2) & 3);
    int acol = (quad ^ gsw) * 8;

    f32x4 zero4 = {0.f, 0.f, 0.f, 0.f};
    f32x4 acc[4][4];
#pragma unroll
    for (int i = 0; i < 4; ++i)
#pragma unroll
        for (int j = 0; j < 4; ++j) acc[i][j] = zero4;

    auto stage = [&](int t, int buf) {
        int k0 = t * 32;
        int ao = buf * 4096 + (w * 32) * 32;
        int bo = 8192 + buf * 4096 + (w * 32) * 32;
        gl2lds16(aptr + k0, smem + ao);
        gl2lds16(aptr + (size_t)16 * K + k0, smem + ao + 16 * 32);
        gl2lds16(bptr + k0, smem + bo);
        gl2lds16(bptr + (size_t)16 * K + k0, smem + bo + 16 * 32);
    };

    stage(0, 0);
    for (int t = 0; t < NT; ++t) {
        int cur = t & 1;
        asm volatile("s_waitcnt vmcnt(0)" ::: "memory");
        __syncthreads();
        if (t + 1 < NT) stage(t + 1, cur ^ 1);
        const _Float16* Asr = smem + cur * 4096;
        const _Float16* Bsr = smem + 8192 + cur * 4096;
        f16x8 af[4], bf[4];
#pragma unroll
        for (int i = 0; i < 4; ++i)
            af[i] = *(const f16x8*)&Asr[(wm * 64 + i * 16 + m16) * 32 + acol];
#pragma unroll
        for (int j = 0; j < 4; ++j)
            bf[j] = *(const f16x8*)&Bsr[(wn * 64 + j * 16 + m16) * 32 + acol];
#pragma unroll
        for (int i = 0; i < 4; ++i)
#pragma unroll
            for (int j = 0; j < 4; ++j)
                acc[i][j] = MFMA16(af[i], bf[j], acc[i][j]);
    }

    if (MODE == 1) {
#pragma unroll
        for (int j = 0; j < 4; ++j) {
            int n = n0 + wn * 64 + j * 16 + m16;
            float bi = bias0[n];
#pragma unroll
            for (int i = 0; i < 4; ++i)
#pragma unroll
                for (int r = 0; r < 4; ++r) {
                    int mg = row0 + wm * 64 + i * 16 + quad * 4 + r;
                    Out[(size_t)mg * HH + n] = acc[i][j][r] + bi;
                }
        }
        return;
    }

    // ---- MODE 0 epilogue: bias (+scale for Q), LDS bounce, coalesced stores ----
    int which = n0 >> 10;                     // 0=Q 1=K 2=V (block is pure)
    const float* bias = (which == 0) ? bias0 : (which == 1) ? bias1 : bias2;
    __syncthreads();
#pragma unroll
    for (int j = 0; j < 4; ++j) {
        int n_local = wn * 64 + j * 16 + m16;
        float bi = bias[(n0 + n_local) & 1023];
#pragma unroll
        for (int i = 0; i < 4; ++i)
#pragma unroll
            for (int r = 0; r < 4; ++r) {
                int m_local = wm * 64 + i * 16 + quad * 4 + r;
                float v = acc[i][j][r] + bi;
                if (which == 0) v *= 0.18033688011112042f;  // (1/sqrt(64))*log2(e)
                if (which == 2) smem[n_local * 132 + m_local] = (_Float16)v;   // transposed
                else            smem[m_local * 132 + n_local] = (_Float16)v;
            }
    }
    __syncthreads();

    int b = row0 >> 11, s0 = row0 & 2047;
    if (which == 2) {
#pragma unroll
        for (int p = 0; p < 8; ++p) {
            int n_local = p * 16 + (tid >> 4);
            int schunk = tid & 15;
            f16x8 v = *(const f16x8*)&smem[n_local * 132 + schunk * 8];
            int nw = (n0 + n_local) & 1023;
            int hh = nw >> 6, d = nw & 63;
            *(f16x8*)&Vt[((size_t)(b * NHH + hh) * HDD + d) * SS + s0 + schunk * 8] = v;
        }
    } else {
        _Float16* dst = (which == 0) ? Qh : Kh;
        int hh0 = (n0 & 1023) >> 6;
#pragma unroll
        for (int p = 0; p < 8; ++p) {
            int m_local = p * 16 + (tid >> 4);
            int seg = tid & 15;
            f16x8 v = *(const f16x8*)&smem[m_local * 132 + seg * 8];
            int hh = hh0 + (seg >> 3), d = (seg & 7) * 8;
            *(f16x8*)&dst[((size_t)(b * NHH + hh) * SS + s0 + m_local) * HDD + d] = v;
        }
    }
}

// ---------------- Flash attention: one 64-row q-tile per block, dbuf K/V staging ----------
// grid (32, NH, B), block 256 (4 waves x 16 q-rows). tq = 31-bx (longest blocks first).
// LDS 41.2 KB -> 3 blocks/CU (12 waves/CU) for latency hiding.
__global__ __launch_bounds__(256, 3) void attn_kernel(
    const _Float16* __restrict__ Qh, const _Float16* __restrict__ Kh,
    const _Float16* __restrict__ Vt, _Float16* __restrict__ Ctx)
{
    __shared__ _Float16 Kb[2][64 * 64];   // dbuf; row-chunks swizzled: chunk ^= row&7
    __shared__ _Float16 Vb[2][64 * 64];
    __shared__ _Float16 Pl[4][16][72];    // per-wave P tile: 64 cols + 8 pad (144B stride)

    int tid = threadIdx.x;
    int w = tid >> 6, l = tid & 63;
    int m16 = l & 15, quad = l >> 4;
    int b = blockIdx.z, h = blockIdx.y;
    int tq = 31 - blockIdx.x;             // longest-first dispatch

    const _Float16* Q = Qh + (size_t)(b * NHH + h) * SS * HDD;
    const _Float16* K = Kh + (size_t)(b * NHH + h) * SS * HDD;
    const _Float16* V = Vt + (size_t)(b * NHH + h) * HDD * SS;

    int qb = tq * 64 + w * 16;
    f16x8 aq0 = *(const f16x8*)(Q + (size_t)(qb + m16) * HDD + quad * 8);
    f16x8 aq1 = *(const f16x8*)(Q + (size_t)(qb + m16) * HDD + 32 + quad * 8);

    // staging: wave w covers rows [w*16, w*16+16), two 8-row instrs per matrix
    int srow = w * 16 + (l >> 3);
    int sch = (l & 7) ^ (l >> 3);
    const _Float16* kg = K + (size_t)srow * HDD + sch * 8;
    const _Float16* vg = V + (size_t)srow * SS + sch * 8;

    auto stage = [&](int t, int buf) {
        int kt = t * 64;
        gl2lds16(kg + (size_t)kt * HDD, &Kb[buf][(w * 16) * 64]);
        gl2lds16(kg + (size_t)(kt + 8) * HDD, &Kb[buf][(w * 16 + 8) * 64]);
        gl2lds16(vg + kt, &Vb[buf][(w * 16) * 64]);
        gl2lds16(vg + (size_t)8 * SS + kt, &Vb[buf][(w * 16 + 8) * 64]);
    };

    int swz = m16 & 7;
    int cka = (quad ^ swz) * 8;
    int ckb = ((quad + 4) ^ swz) * 8;

    f32x4 zero4 = {0.f, 0.f, 0.f, 0.f};
    f32x4 o[4];
#pragma unroll
    for (int c = 0; c < 4; ++c) o[c] = zero4;
    float ls[4] = {0.f, 0.f, 0.f, 0.f};

    stage(0, 0);
    for (int t = 0; t <= tq; ++t) {
        int cur = t & 1;
        int kt = t * 64;
        asm volatile("s_waitcnt vmcnt(0)" ::: "memory");
        __syncthreads();
        if (t < tq) stage(t + 1, cur ^ 1);

        f16x8 bk[4][2], bv[4][2];
#pragma unroll
        for (int s = 0; s < 4; ++s) {
            const _Float16* kr = &Kb[cur][(s * 16 + m16) * 64];
            bk[s][0] = *(const f16x8*)(kr + cka);
            bk[s][1] = *(const f16x8*)(kr + ckb);
        }
#pragma unroll
        for (int c = 0; c < 4; ++c) {
            const _Float16* vr = &Vb[cur][(c * 16 + m16) * 64];
            bv[c][0] = *(const f16x8*)(vr + cka);
            bv[c][1] = *(const f16x8*)(vr + ckb);
        }

        f32x4 sc[4];
#pragma unroll
        for (int s = 0; s < 4; ++s) {
            sc[s] = MFMA16(aq0, bk[s][0], zero4);
            sc[s] = MFMA16(aq1, bk[s][1], sc[s]);
        }

#pragma unroll
        for (int s = 0; s < 4; ++s) {
            int key = kt + s * 16 + m16;
#pragma unroll
            for (int r = 0; r < 4; ++r) {
                int qrow = qb + quad * 4 + r;
                float p = (key > qrow) ? 0.0f : exp2f(sc[s][r]);
                ls[r] += p;
                Pl[w][quad * 4 + r][s * 16 + m16] = (_Float16)p;
            }
        }
        asm volatile("s_waitcnt lgkmcnt(0)" ::: "memory");

        f16x8 pf0 = *(const f16x8*)&Pl[w][m16][quad * 8];
        f16x8 pf1 = *(const f16x8*)&Pl[w][m16][32 + quad * 8];
#pragma unroll
        for (int c = 0; c < 4; ++c) {
            o[c] = MFMA16(pf0, bv[c][0], o[c]);
            o[c] = MFMA16(pf1, bv[c][1], o[c]);
        }
        // no trailing barrier: next step's top barrier orders buf reuse, and each wave's
        // lgkm drain above guarantees its Kb/Vb reads completed before it re-stages.
    }

    // epilogue: normalize and store
#pragma unroll
    for (int r = 0; r < 4; ++r) {
        float rs = ls[r];
#pragma unroll
        for (int off = 1; off < 16; off <<= 1) rs += __shfl_xor(rs, off);
        float inv = 1.0f / rs;
        size_t rowoff = ((size_t)(b * SS) + qb + quad * 4 + r) * HH + h * HDD;
#pragma unroll
        for (int c = 0; c < 4; ++c)
            Ctx[rowoff + c * 16 + m16] = (_Float16)(o[c][r] * inv);
    }
}

extern "C" void kernel_launch(void* const* d_in, const int* in_sizes, int n_in,
                              void* d_out, int out_size, void* d_ws, size_t ws_size,
                              hipStream_t stream) {
    const float* hs = (const float*)d_in[0];
    const float* Wq = (const float*)d_in[1];
    const float* bq = (const float*)d_in[2];
    const float* Wk = (const float*)d_in[3];
    const float* bk = (const float*)d_in[4];
    const float* Wv = (const float*)d_in[5];
    const float* bv = (const float*)d_in[6];
    const float* Wo = (const float*)d_in[7];
    const float* bo = (const float*)d_in[8];
    float* out = (float*)d_out;

    size_t off = 0;
    auto alloc = [&](size_t bytes) {
        void* p = (char*)d_ws + off;
        off += (bytes + 255) & ~(size_t)255;
        return p;
    };
    _Float16* Xh    = (_Float16*)alloc((size_t)MM * HH * 2);
    _Float16* WqkvT = (_Float16*)alloc((size_t)3 * HH * HH * 2);
    _Float16* WoT   = (_Float16*)alloc((size_t)HH * HH * 2);
    _Float16* Qh    = (_Float16*)alloc((size_t)BB * NHH * SS * HDD * 2);
    _Float16* Kh    = (_Float16*)alloc((size_t)BB * NHH * SS * HDD * 2);
    _Float16* Vt    = (_Float16*)alloc((size_t)BB * NHH * SS * HDD * 2);
    _Float16* Ctx   = (_Float16*)alloc((size_t)MM * HH * 2);

    cast4_kernel<<<(MM * HH / 4 + 255) / 256, 256, 0, stream>>>(hs, Xh, MM * HH / 4);
    transpose_kernel<<<dim3(16, 16, 4), 256, 0, stream>>>(Wq, Wk, Wv, Wo, WqkvT, WoT);
    gemm128_kernel<0><<<dim3(QKV_N / 128, MM / 128), 256, 0, stream>>>(
        Xh, WqkvT, bq, bk, bv, Qh, Kh, Vt, nullptr);
    attn_kernel<<<dim3(32, NHH, BB), 256, 0, stream>>>(Qh, Kh, Vt, Ctx);
    gemm128_kernel<1><<<dim3(HH / 128, MM / 128), 256, 0, stream>>>(
        Ctx, WoT, bo, bo, bo, nullptr, nullptr, nullptr, out);
}

// Round 10
// 201.614 us; speedup vs baseline: 1.1653x; 1.1653x over previous
//
#include <hip/hip_runtime.h>
#include <hip/hip_bf16.h>

// Problem constants
#define BB 2
#define SS 2048
#define HH 1024
#define NHH 16
#define HDD 64
#define MM (BB*SS)        // 4096
#define QKV_N (3*HH)      // 3072

typedef _Float16 f16x8 __attribute__((ext_vector_type(8)));
typedef _Float16 f16x4 __attribute__((ext_vector_type(4)));
typedef float f32x4 __attribute__((ext_vector_type(4)));

#define MFMA16(a,b,c) __builtin_amdgcn_mfma_f32_16x16x32_f16((a),(b),(c),0,0,0)

// async global->LDS 16B per lane; LDS dest = wave-uniform base + lane*16
__device__ __forceinline__ void gl2lds16(const _Float16* g, _Float16* l) {
    __builtin_amdgcn_global_load_lds(
        (const __attribute__((address_space(1))) void*)g,
        (__attribute__((address_space(3))) void*)l, 16, 0, 0);
}

// ---------------- cast fp32 -> fp16, vectorized ----------------
__global__ void cast4_kernel(const float* __restrict__ x, _Float16* __restrict__ y, int n4) {
    int i = blockIdx.x * blockDim.x + threadIdx.x;
    if (i < n4) {
        float4 v = ((const float4*)x)[i];
        f16x4 h = {(_Float16)v.x, (_Float16)v.y, (_Float16)v.z, (_Float16)v.w};
        ((f16x4*)y)[i] = h;
    }
}

// ---------------- transpose-cast W[k][n] fp32 -> Wt[n][k] fp16, 64x64 tiles -------------
__global__ __launch_bounds__(256) void transpose_kernel(
    const float* __restrict__ W0, const float* __restrict__ W1,
    const float* __restrict__ W2, const float* __restrict__ W3,
    _Float16* __restrict__ WqkvT, _Float16* __restrict__ WoT)
{
    __shared__ float t[64][65];
    int z = blockIdx.z;
    const float* src = (z == 0) ? W0 : (z == 1) ? W1 : (z == 2) ? W2 : W3;
    _Float16* dst = (z < 3) ? (WqkvT + (size_t)z * HH * HH) : WoT;
    int k0 = blockIdx.y * 64, n0 = blockIdx.x * 64;
    int tid = threadIdx.x;

#pragma unroll
    for (int p = 0; p < 4; ++p) {
        int row = p * 16 + (tid >> 4);
        int col4 = (tid & 15) * 4;
        float4 v = *(const float4*)&src[(size_t)(k0 + row) * HH + n0 + col4];
        t[row][col4 + 0] = v.x; t[row][col4 + 1] = v.y;
        t[row][col4 + 2] = v.z; t[row][col4 + 3] = v.w;
    }
    __syncthreads();
#pragma unroll
    for (int p = 0; p < 2; ++p) {
        int nc = p * 32 + (tid >> 3);
        int ch = tid & 7;
        f16x8 o;
#pragma unroll
        for (int j = 0; j < 8; ++j) o[j] = (_Float16)t[ch * 8 + j][nc];
        *(f16x8*)&dst[(size_t)(n0 + nc) * HH + k0 + ch * 8] = o;
    }
}

// ---------------- MFMA GEMM 128x128 tile, 3-stage pipeline, raw barrier ----------------
// Stage s: A @ s*4096, B @ 12288+s*4096 (elements). vmcnt(4) partial waits keep the
// next stage's DMA in flight across the barrier (AITER pattern; m139 raw-barrier).
template<int MODE>
__global__ __launch_bounds__(256) void gemm128_kernel(
    const _Float16* __restrict__ A, const _Float16* __restrict__ Bt,
    const float* __restrict__ bias0, const float* __restrict__ bias1, const float* __restrict__ bias2,
    _Float16* __restrict__ Qh, _Float16* __restrict__ Kh, _Float16* __restrict__ Vt,
    float* __restrict__ Out)
{
    const int K = HH;
    const int NT = K / 32;
    __shared__ _Float16 smem[24576];          // 49152 B: 3-stage bufs U epilogue tile 128x132

    int row0 = blockIdx.y * 128, n0 = blockIdx.x * 128;
    int tid = threadIdx.x;
    int w = tid >> 6, l = tid & 63, m16 = l & 15, quad = l >> 4;
    int wm = w >> 1, wn = w & 1;

    int srow = w * 32 + (l >> 2);
    int sch = (l & 3) ^ ((l >> 2) & 3) ^ ((l >> 4) & 3);
    const _Float16* aptr = A + (size_t)(row0 + srow) * K + sch * 8;
    const _Float16* bptr = Bt + (size_t)(n0 + srow) * K + sch * 8;

    int gsw = (m16 & 3) ^ ((m16 >> 2) & 3);
    int acol = (quad ^ gsw) * 8;

    f32x4 zero4 = {0.f, 0.f, 0.f, 0.f};
    f32x4 acc[4][4];
#pragma unroll
    for (int i = 0; i < 4; ++i)
#pragma unroll
        for (int j = 0; j < 4; ++j) acc[i][j] = zero4;

    auto stage = [&](int t, int s) {
        int k0 = t * 32;
        int ao = s * 4096 + (w * 32) * 32;
        int bo = 12288 + s * 4096 + (w * 32) * 32;
        gl2lds16(aptr + k0, smem + ao);
        gl2lds16(aptr + (size_t)16 * K + k0, smem + ao + 16 * 32);
        gl2lds16(bptr + k0, smem + bo);
        gl2lds16(bptr + (size_t)16 * K + k0, smem + bo + 16 * 32);
    };

    stage(0, 0);
    stage(1, 1);
    int cur = 0;
    for (int t = 0; t < NT; ++t) {
        // own stage(t) done; stage(t+1) may remain in flight (4 loads)
        if (t < NT - 1) asm volatile("s_waitcnt vmcnt(4)" ::: "memory");
        else            asm volatile("s_waitcnt vmcnt(0)" ::: "memory");
        asm volatile("s_barrier" ::: "memory");   // raw: no compiler-forced full drain
        if (t + 2 < NT) {
            int nxt = cur + 2; if (nxt >= 3) nxt -= 3;   // (cur+2) % 3 — ring index
            stage(t + 2, nxt);
        }
        const _Float16* Asr = smem + cur * 4096;
        const _Float16* Bsr = smem + 12288 + cur * 4096;
        f16x8 af[4], bf[4];
#pragma unroll
        for (int i = 0; i < 4; ++i)
            af[i] = *(const f16x8*)&Asr[(wm * 64 + i * 16 + m16) * 32 + acol];
#pragma unroll
        for (int j = 0; j < 4; ++j)
            bf[j] = *(const f16x8*)&Bsr[(wn * 64 + j * 16 + m16) * 32 + acol];
#pragma unroll
        for (int i = 0; i < 4; ++i)
#pragma unroll
            for (int j = 0; j < 4; ++j)
                acc[i][j] = MFMA16(af[i], bf[j], acc[i][j]);
        cur = (cur == 2) ? 0 : cur + 1;
    }

    if (MODE == 1) {
#pragma unroll
        for (int j = 0; j < 4; ++j) {
            int n = n0 + wn * 64 + j * 16 + m16;
            float bi = bias0[n];
#pragma unroll
            for (int i = 0; i < 4; ++i)
#pragma unroll
                for (int r = 0; r < 4; ++r) {
                    int mg = row0 + wm * 64 + i * 16 + quad * 4 + r;
                    Out[(size_t)mg * HH + n] = acc[i][j][r] + bi;
                }
        }
        return;
    }

    // ---- MODE 0 epilogue: bias (+scale for Q), LDS bounce, coalesced stores ----
    int which = n0 >> 10;                     // 0=Q 1=K 2=V (block is pure)
    const float* bias = (which == 0) ? bias0 : (which == 1) ? bias1 : bias2;
    __syncthreads();                          // full barrier (with drain) before smem reuse
#pragma unroll
    for (int j = 0; j < 4; ++j) {
        int n_local = wn * 64 + j * 16 + m16;
        float bi = bias[(n0 + n_local) & 1023];
#pragma unroll
        for (int i = 0; i < 4; ++i)
#pragma unroll
            for (int r = 0; r < 4; ++r) {
                int m_local = wm * 64 + i * 16 + quad * 4 + r;
                float v = acc[i][j][r] + bi;
                if (which == 0) v *= 0.18033688011112042f;  // (1/sqrt(64))*log2(e)
                if (which == 2) smem[n_local * 132 + m_local] = (_Float16)v;   // transposed
                else            smem[m_local * 132 + n_local] = (_Float16)v;
            }
    }
    __syncthreads();

    int b = row0 >> 11, s0 = row0 & 2047;
    if (which == 2) {
#pragma unroll
        for (int p = 0; p < 8; ++p) {
            int n_local = p * 16 + (tid >> 4);
            int schunk = tid & 15;
            f16x8 v = *(const f16x8*)&smem[n_local * 132 + schunk * 8];
            int nw = (n0 + n_local) & 1023;
            int hh = nw >> 6, d = nw & 63;
            *(f16x8*)&Vt[((size_t)(b * NHH + hh) * HDD + d) * SS + s0 + schunk * 8] = v;
        }
    } else {
        _Float16* dst = (which == 0) ? Qh : Kh;
        int hh0 = (n0 & 1023) >> 6;
#pragma unroll
        for (int p = 0; p < 8; ++p) {
            int m_local = p * 16 + (tid >> 4);
            int seg = tid & 15;
            f16x8 v = *(const f16x8*)&smem[m_local * 132 + seg * 8];
            int hh = hh0 + (seg >> 3), d = (seg & 7) * 8;
            *(f16x8*)&dst[((size_t)(b * NHH + hh) * SS + s0 + m_local) * HDD + d] = v;
        }
    }
}

// ---------------- Flash attention: paired q-tiles, fused bodies, 3-stage K/V pipeline ----
// grid (16, NH, B), block 256. Block bx handles q-tiles tA=bx and tB=31-bx.
// Stage s: K @ KV[s*8192], V @ KV[s*8192+4096]. Raw barrier + vmcnt(4) partial waits.
__global__ __launch_bounds__(256, 2) void attn_kernel(
    const _Float16* __restrict__ Qh, const _Float16* __restrict__ Kh,
    const _Float16* __restrict__ Vt, _Float16* __restrict__ Ctx)
{
    __shared__ _Float16 KV[3 * 8192];     // 49152 B, 3-stage K+V
    __shared__ _Float16 Pl[4][2][16][72]; // per-wave P tiles: 64 cols + 8 pad (144B stride)

    int tid = threadIdx.x;
    int w = tid >> 6, l = tid & 63;
    int m16 = l & 15, quad = l >> 4;
    int b = blockIdx.z, h = blockIdx.y;
    int tA = blockIdx.x, tB = 31 - tA;

    const _Float16* Q = Qh + (size_t)(b * NHH + h) * SS * HDD;
    const _Float16* K = Kh + (size_t)(b * NHH + h) * SS * HDD;
    const _Float16* V = Vt + (size_t)(b * NHH + h) * HDD * SS;

    int qbA = tA * 64 + w * 16, qbB = tB * 64 + w * 16;
    f16x8 aqA0 = *(const f16x8*)(Q + (size_t)(qbA + m16) * HDD + quad * 8);
    f16x8 aqA1 = *(const f16x8*)(Q + (size_t)(qbA + m16) * HDD + 32 + quad * 8);
    f16x8 aqB0 = *(const f16x8*)(Q + (size_t)(qbB + m16) * HDD + quad * 8);
    f16x8 aqB1 = *(const f16x8*)(Q + (size_t)(qbB + m16) * HDD + 32 + quad * 8);

    // staging: wave w covers rows [w*16, w*16+16), two 8-row instrs per matrix
    int srow = w * 16 + (l >> 3);
    int sch = (l & 7) ^ (l >> 3);
    const _Float16* kg = K + (size_t)srow * HDD + sch * 8;
    const _Float16* vg = V + (size_t)srow * SS + sch * 8;

    auto stage = [&](int t, int s) {
        int kt = t * 64;
        _Float16* kb = &KV[s * 8192];
        _Float16* vb = &KV[s * 8192 + 4096];
        gl2lds16(kg + (size_t)kt * HDD, kb + (w * 16) * 64);
        gl2lds16(kg + (size_t)(kt + 8) * HDD, kb + (w * 16 + 8) * 64);
        gl2lds16(vg + kt, vb + (w * 16) * 64);
        gl2lds16(vg + (size_t)8 * SS + kt, vb + (w * 16 + 8) * 64);
    };

    int swz = m16 & 7;
    int cka = (quad ^ swz) * 8;
    int ckb = ((quad + 4) ^ swz) * 8;

    f32x4 zero4 = {0.f, 0.f, 0.f, 0.f};
    f32x4 oA[4], oB[4];
#pragma unroll
    for (int c = 0; c < 4; ++c) { oA[c] = zero4; oB[c] = zero4; }
    float lsA[4] = {0.f, 0.f, 0.f, 0.f}, lsB[4] = {0.f, 0.f, 0.f, 0.f};

    stage(0, 0);
    if (1 <= tB) stage(1, 1);
    int cur = 0;
    for (int t = 0; t <= tB; ++t) {
        int kt = t * 64;
        bool doA = (t <= tA);
        // own stage(t) done; stage(t+1) (if issued) may remain in flight
        if (t < tB) asm volatile("s_waitcnt vmcnt(4)" ::: "memory");
        else        asm volatile("s_waitcnt vmcnt(0)" ::: "memory");
        asm volatile("s_barrier" ::: "memory");
        if (t + 2 <= tB) {
            int nxt = cur + 2; if (nxt >= 3) nxt -= 3;   // (cur+2) % 3 — ring index
            stage(t + 2, nxt);
        }

        const _Float16* kb = &KV[cur * 8192];
        const _Float16* vb = &KV[cur * 8192 + 4096];
        f16x8 bk[4][2], bv[4][2];
#pragma unroll
        for (int s = 0; s < 4; ++s) {
            const _Float16* kr = kb + (s * 16 + m16) * 64;
            bk[s][0] = *(const f16x8*)(kr + cka);
            bk[s][1] = *(const f16x8*)(kr + ckb);
        }
#pragma unroll
        for (int c = 0; c < 4; ++c) {
            const _Float16* vr = vb + (c * 16 + m16) * 64;
            bv[c][0] = *(const f16x8*)(vr + cka);
            bv[c][1] = *(const f16x8*)(vr + ckb);
        }

        // QK^T for both q-tiles (independent chains)
        f32x4 scB[4], scA[4];
#pragma unroll
        for (int s = 0; s < 4; ++s) {
            scB[s] = MFMA16(aqB0, bk[s][0], zero4);
            scB[s] = MFMA16(aqB1, bk[s][1], scB[s]);
        }
        if (doA) {
#pragma unroll
            for (int s = 0; s < 4; ++s) {
                scA[s] = MFMA16(aqA0, bk[s][0], zero4);
                scA[s] = MFMA16(aqA1, bk[s][1], scA[s]);
            }
        }

        // mask + exp2 + P writes for both tiles, then ONE lgkm drain
#pragma unroll
        for (int s = 0; s < 4; ++s) {
            int key = kt + s * 16 + m16;
#pragma unroll
            for (int r = 0; r < 4; ++r) {
                int qrow = qbB + quad * 4 + r;
                float p = (key > qrow) ? 0.0f : exp2f(scB[s][r]);
                lsB[r] += p;
                Pl[w][0][quad * 4 + r][s * 16 + m16] = (_Float16)p;
            }
        }
        if (doA) {
#pragma unroll
            for (int s = 0; s < 4; ++s) {
                int key = kt + s * 16 + m16;
#pragma unroll
                for (int r = 0; r < 4; ++r) {
                    int qrow = qbA + quad * 4 + r;
                    float p = (key > qrow) ? 0.0f : exp2f(scA[s][r]);
                    lsA[r] += p;
                    Pl[w][1][quad * 4 + r][s * 16 + m16] = (_Float16)p;
                }
            }
        }
        asm volatile("s_waitcnt lgkmcnt(0)" ::: "memory");

        f16x8 pfB0 = *(const f16x8*)&Pl[w][0][m16][quad * 8];
        f16x8 pfB1 = *(const f16x8*)&Pl[w][0][m16][32 + quad * 8];
#pragma unroll
        for (int c = 0; c < 4; ++c) {
            oB[c] = MFMA16(pfB0, bv[c][0], oB[c]);
            oB[c] = MFMA16(pfB1, bv[c][1], oB[c]);
        }
        if (doA) {
            f16x8 pfA0 = *(const f16x8*)&Pl[w][1][m16][quad * 8];
            f16x8 pfA1 = *(const f16x8*)&Pl[w][1][m16][32 + quad * 8];
#pragma unroll
            for (int c = 0; c < 4; ++c) {
                oA[c] = MFMA16(pfA0, bv[c][0], oA[c]);
                oA[c] = MFMA16(pfA1, bv[c][1], oA[c]);
            }
        }
        cur = (cur == 2) ? 0 : cur + 1;
    }

    // epilogue: normalize and store both q-subtiles
#pragma unroll
    for (int half = 0; half < 2; ++half) {
        f32x4* o = half ? oB : oA;
        float* ls = half ? lsB : lsA;
        int qb = half ? qbB : qbA;
#pragma unroll
        for (int r = 0; r < 4; ++r) {
            float rs = ls[r];
#pragma unroll
            for (int off = 1; off < 16; off <<= 1) rs += __shfl_xor(rs, off);
            float inv = 1.0f / rs;
            size_t rowoff = ((size_t)(b * SS) + qb + quad * 4 + r) * HH + h * HDD;
#pragma unroll
            for (int c = 0; c < 4; ++c)
                Ctx[rowoff + c * 16 + m16] = (_Float16)(o[c][r] * inv);
        }
    }
}

extern "C" void kernel_launch(void* const* d_in, const int* in_sizes, int n_in,
                              void* d_out, int out_size, void* d_ws, size_t ws_size,
                              hipStream_t stream) {
    const float* hs = (const float*)d_in[0];
    const float* Wq = (const float*)d_in[1];
    const float* bq = (const float*)d_in[2];
    const float* Wk = (const float*)d_in[3];
    const float* bk = (const float*)d_in[4];
    const float* Wv = (const float*)d_in[5];
    const float* bv = (const float*)d_in[6];
    const float* Wo = (const float*)d_in[7];
    const float* bo = (const float*)d_in[8];
    float* out = (float*)d_out;

    size_t off = 0;
    auto alloc = [&](size_t bytes) {
        void* p = (char*)d_ws + off;
        off += (bytes + 255) & ~(size_t)255;
        return p;
    };
    _Float16* Xh    = (_Float16*)alloc((size_t)MM * HH * 2);
    _Float16* WqkvT = (_Float16*)alloc((size_t)3 * HH * HH * 2);
    _Float16* WoT   = (_Float16*)alloc((size_t)HH * HH * 2);
    _Float16* Qh    = (_Float16*)alloc((size_t)BB * NHH * SS * HDD * 2);
    _Float16* Kh    = (_Float16*)alloc((size_t)BB * NHH * SS * HDD * 2);
    _Float16* Vt    = (_Float16*)alloc((size_t)BB * NHH * SS * HDD * 2);
    _Float16* Ctx   = (_Float16*)alloc((size_t)MM * HH * 2);

    cast4_kernel<<<(MM * HH / 4 + 255) / 256, 256, 0, stream>>>(hs, Xh, MM * HH / 4);
    transpose_kernel<<<dim3(16, 16, 4), 256, 0, stream>>>(Wq, Wk, Wv, Wo, WqkvT, WoT);
    gemm128_kernel<0><<<dim3(QKV_N / 128, MM / 128), 256, 0, stream>>>(
        Xh, WqkvT, bq, bk, bv, Qh, Kh, Vt, nullptr);
    attn_kernel<<<dim3(16, NHH, BB), 256, 0, stream>>>(Qh, Kh, Vt, Ctx);
    gemm128_kernel<1><<<dim3(HH / 128, MM / 128), 256, 0, stream>>>(
        Ctx, WoT, bo, bo, bo, nullptr, nullptr, nullptr, out);
}

// Round 11
// 195.643 us; speedup vs baseline: 1.2008x; 1.0305x over previous
//
#include <hip/hip_runtime.h>
#include <hip/hip_bf16.h>

// Problem constants
#define BB 2
#define SS 2048
#define HH 1024
#define NHH 16
#define HDD 64
#define MM (BB*SS)        // 4096
#define QKV_N (3*HH)      // 3072

typedef _Float16 f16x8 __attribute__((ext_vector_type(8)));
typedef _Float16 f16x4 __attribute__((ext_vector_type(4)));
typedef float f32x4 __attribute__((ext_vector_type(4)));

#define MFMA16(a,b,c)  __builtin_amdgcn_mfma_f32_16x16x32_f16((a),(b),(c),0,0,0)
#define MFMA16K16(a,b,c) __builtin_amdgcn_mfma_f32_16x16x16f16((a),(b),(c),0,0,0)

// async global->LDS 16B per lane; LDS dest = wave-uniform base + lane*16
__device__ __forceinline__ void gl2lds16(const _Float16* g, _Float16* l) {
    __builtin_amdgcn_global_load_lds(
        (const __attribute__((address_space(1))) void*)g,
        (__attribute__((address_space(3))) void*)l, 16, 0, 0);
}

// ---------------- cast fp32 -> fp16, vectorized ----------------
__global__ void cast4_kernel(const float* __restrict__ x, _Float16* __restrict__ y, int n4) {
    int i = blockIdx.x * blockDim.x + threadIdx.x;
    if (i < n4) {
        float4 v = ((const float4*)x)[i];
        f16x4 h = {(_Float16)v.x, (_Float16)v.y, (_Float16)v.z, (_Float16)v.w};
        ((f16x4*)y)[i] = h;
    }
}

// ---------------- transpose-cast W[k][n] fp32 -> Wt[n][k] fp16, 64x64 tiles -------------
__global__ __launch_bounds__(256) void transpose_kernel(
    const float* __restrict__ W0, const float* __restrict__ W1,
    const float* __restrict__ W2, const float* __restrict__ W3,
    _Float16* __restrict__ WqkvT, _Float16* __restrict__ WoT)
{
    __shared__ float t[64][65];
    int z = blockIdx.z;
    const float* src = (z == 0) ? W0 : (z == 1) ? W1 : (z == 2) ? W2 : W3;
    _Float16* dst = (z < 3) ? (WqkvT + (size_t)z * HH * HH) : WoT;
    int k0 = blockIdx.y * 64, n0 = blockIdx.x * 64;
    int tid = threadIdx.x;

#pragma unroll
    for (int p = 0; p < 4; ++p) {
        int row = p * 16 + (tid >> 4);
        int col4 = (tid & 15) * 4;
        float4 v = *(const float4*)&src[(size_t)(k0 + row) * HH + n0 + col4];
        t[row][col4 + 0] = v.x; t[row][col4 + 1] = v.y;
        t[row][col4 + 2] = v.z; t[row][col4 + 3] = v.w;
    }
    __syncthreads();
#pragma unroll
    for (int p = 0; p < 2; ++p) {
        int nc = p * 32 + (tid >> 3);
        int ch = tid & 7;
        f16x8 o;
#pragma unroll
        for (int j = 0; j < 8; ++j) o[j] = (_Float16)t[ch * 8 + j][nc];
        *(f16x8*)&dst[(size_t)(n0 + nc) * HH + k0 + ch * 8] = o;
    }
}

// ---------------- MFMA GEMM 128x128 tile, 3-stage pipeline, raw barrier ----------------
template<int MODE>
__global__ __launch_bounds__(256) void gemm128_kernel(
    const _Float16* __restrict__ A, const _Float16* __restrict__ Bt,
    const float* __restrict__ bias0, const float* __restrict__ bias1, const float* __restrict__ bias2,
    _Float16* __restrict__ Qh, _Float16* __restrict__ Kh, _Float16* __restrict__ Vt,
    float* __restrict__ Out)
{
    const int K = HH;
    const int NT = K / 32;
    __shared__ _Float16 smem[24576];          // 49152 B: 3-stage bufs U epilogue tile 128x132

    int row0 = blockIdx.y * 128, n0 = blockIdx.x * 128;
    int tid = threadIdx.x;
    int w = tid >> 6, l = tid & 63, m16 = l & 15, quad = l >> 4;
    int wm = w >> 1, wn = w & 1;

    int srow = w * 32 + (l >> 2);
    int sch = (l & 3) ^ ((l >> 2) & 3) ^ ((l >> 4) & 3);
    const _Float16* aptr = A + (size_t)(row0 + srow) * K + sch * 8;
    const _Float16* bptr = Bt + (size_t)(n0 + srow) * K + sch * 8;

    int gsw = (m16 & 3) ^ ((m16 >> 2) & 3);
    int acol = (quad ^ gsw) * 8;

    f32x4 zero4 = {0.f, 0.f, 0.f, 0.f};
    f32x4 acc[4][4];
#pragma unroll
    for (int i = 0; i < 4; ++i)
#pragma unroll
        for (int j = 0; j < 4; ++j) acc[i][j] = zero4;

    auto stage = [&](int t, int s) {
        int k0 = t * 32;
        int ao = s * 4096 + (w * 32) * 32;
        int bo = 12288 + s * 4096 + (w * 32) * 32;
        gl2lds16(aptr + k0, smem + ao);
        gl2lds16(aptr + (size_t)16 * K + k0, smem + ao + 16 * 32);
        gl2lds16(bptr + k0, smem + bo);
        gl2lds16(bptr + (size_t)16 * K + k0, smem + bo + 16 * 32);
    };

    stage(0, 0);
    stage(1, 1);
    int cur = 0;
    for (int t = 0; t < NT; ++t) {
        if (t < NT - 1) asm volatile("s_waitcnt vmcnt(4)" ::: "memory");
        else            asm volatile("s_waitcnt vmcnt(0)" ::: "memory");
        asm volatile("s_barrier" ::: "memory");
        if (t + 2 < NT) {
            int nxt = cur + 2; if (nxt >= 3) nxt -= 3;
            stage(t + 2, nxt);
        }
        const _Float16* Asr = smem + cur * 4096;
        const _Float16* Bsr = smem + 12288 + cur * 4096;
        f16x8 af[4], bf[4];
#pragma unroll
        for (int i = 0; i < 4; ++i)
            af[i] = *(const f16x8*)&Asr[(wm * 64 + i * 16 + m16) * 32 + acol];
#pragma unroll
        for (int j = 0; j < 4; ++j)
            bf[j] = *(const f16x8*)&Bsr[(wn * 64 + j * 16 + m16) * 32 + acol];
#pragma unroll
        for (int i = 0; i < 4; ++i)
#pragma unroll
            for (int j = 0; j < 4; ++j)
                acc[i][j] = MFMA16(af[i], bf[j], acc[i][j]);
        cur = (cur == 2) ? 0 : cur + 1;
    }

    if (MODE == 1) {
#pragma unroll
        for (int j = 0; j < 4; ++j) {
            int n = n0 + wn * 64 + j * 16 + m16;
            float bi = bias0[n];
#pragma unroll
            for (int i = 0; i < 4; ++i)
#pragma unroll
                for (int r = 0; r < 4; ++r) {
                    int mg = row0 + wm * 64 + i * 16 + quad * 4 + r;
                    Out[(size_t)mg * HH + n] = acc[i][j][r] + bi;
                }
        }
        return;
    }

    // ---- MODE 0 epilogue: bias (+scale for Q), LDS bounce, coalesced stores ----
    int which = n0 >> 10;                     // 0=Q 1=K 2=V (block is pure)
    const float* bias = (which == 0) ? bias0 : (which == 1) ? bias1 : bias2;
    __syncthreads();
#pragma unroll
    for (int j = 0; j < 4; ++j) {
        int n_local = wn * 64 + j * 16 + m16;
        float bi = bias[(n0 + n_local) & 1023];
#pragma unroll
        for (int i = 0; i < 4; ++i)
#pragma unroll
            for (int r = 0; r < 4; ++r) {
                int m_local = wm * 64 + i * 16 + quad * 4 + r;
                float v = acc[i][j][r] + bi;
                if (which == 0) v *= 0.18033688011112042f;  // (1/sqrt(64))*log2(e)
                if (which == 2) smem[n_local * 132 + m_local] = (_Float16)v;   // transposed
                else            smem[m_local * 132 + n_local] = (_Float16)v;
            }
    }
    __syncthreads();

    int b = row0 >> 11, s0 = row0 & 2047;
    if (which == 2) {
#pragma unroll
        for (int p = 0; p < 8; ++p) {
            int n_local = p * 16 + (tid >> 4);
            int schunk = tid & 15;
            f16x8 v = *(const f16x8*)&smem[n_local * 132 + schunk * 8];
            int nw = (n0 + n_local) & 1023;
            int hh = nw >> 6, d = nw & 63;
            *(f16x8*)&Vt[((size_t)(b * NHH + hh) * HDD + d) * SS + s0 + schunk * 8] = v;
        }
    } else {
        _Float16* dst = (which == 0) ? Qh : Kh;
        int hh0 = (n0 & 1023) >> 6;
#pragma unroll
        for (int p = 0; p < 8; ++p) {
            int m_local = p * 16 + (tid >> 4);
            int seg = tid & 15;
            f16x8 v = *(const f16x8*)&smem[m_local * 132 + seg * 8];
            int hh = hh0 + (seg >> 3), d = (seg & 7) * 8;
            *(f16x8*)&dst[((size_t)(b * NHH + hh) * SS + s0 + m_local) * HDD + d] = v;
        }
    }
}

// ---------------- Flash attention: S^T formulation — P stays in registers ----------------
// S^T = MFMA(A=K, B=Q): lane holds q=lane&15, key=quad*4+r -> exactly the K=16 MFMA
// B-operand layout. PV: O^T = MFMA16x16x16(A=V^T, B=P^T) straight from registers.
// grid (16, NH, B), block 256; paired q-tiles tA=bx, tB=31-bx; 3-stage K/V staging.
__global__ __launch_bounds__(256, 2) void attn_kernel(
    const _Float16* __restrict__ Qh, const _Float16* __restrict__ Kh,
    const _Float16* __restrict__ Vt, _Float16* __restrict__ Ctx)
{
    __shared__ _Float16 KV[3 * 8192];     // 49152 B, 3-stage K+V (no P buffer needed)

    int tid = threadIdx.x;
    int w = tid >> 6, l = tid & 63;
    int m16 = l & 15, quad = l >> 4;
    int b = blockIdx.z, h = blockIdx.y;
    int tA = blockIdx.x, tB = 31 - tA;

    const _Float16* Q = Qh + (size_t)(b * NHH + h) * SS * HDD;
    const _Float16* K = Kh + (size_t)(b * NHH + h) * SS * HDD;
    const _Float16* V = Vt + (size_t)(b * NHH + h) * HDD * SS;

    int qbA = tA * 64 + w * 16, qbB = tB * 64 + w * 16;
    int qA = qbA + m16, qB = qbB + m16;          // this lane's q row (S^T: q = lane&15)
    // Q fragments (B-operand: lane&15 = q, k = d = quad*8+j) — same addresses as before
    f16x8 aqA0 = *(const f16x8*)(Q + (size_t)qA * HDD + quad * 8);
    f16x8 aqA1 = *(const f16x8*)(Q + (size_t)qA * HDD + 32 + quad * 8);
    f16x8 aqB0 = *(const f16x8*)(Q + (size_t)qB * HDD + quad * 8);
    f16x8 aqB1 = *(const f16x8*)(Q + (size_t)qB * HDD + 32 + quad * 8);

    // staging: wave w covers rows [w*16, w*16+16), two 8-row instrs per matrix
    int srow = w * 16 + (l >> 3);
    int sch = (l & 7) ^ (l >> 3);
    const _Float16* kg = K + (size_t)srow * HDD + sch * 8;
    const _Float16* vg = V + (size_t)srow * SS + sch * 8;

    auto stage = [&](int t, int s) {
        int kt = t * 64;
        _Float16* kb = &KV[s * 8192];
        _Float16* vb = &KV[s * 8192 + 4096];
        gl2lds16(kg + (size_t)kt * HDD, kb + (w * 16) * 64);
        gl2lds16(kg + (size_t)(kt + 8) * HDD, kb + (w * 16 + 8) * 64);
        gl2lds16(vg + kt, vb + (w * 16) * 64);
        gl2lds16(vg + (size_t)8 * SS + kt, vb + (w * 16 + 8) * 64);
    };

    int swz = m16 & 7;
    int cka = (quad ^ swz) * 8;          // K-frag d-chunk 0..31
    int ckb = ((quad + 4) ^ swz) * 8;    // K-frag d-chunk 32..63
    // V^T A-frag (K=16): row d = c*16+m16, keys s*16+quad*4..+3 (8B), swizzle-adjusted
    int vco[4];
#pragma unroll
    for (int s = 0; s < 4; ++s)
        vco[s] = (((s * 2 + (quad >> 1)) ^ swz) * 8) + (quad & 1) * 4;

    f32x4 zero4 = {0.f, 0.f, 0.f, 0.f};
    f32x4 oA[4], oB[4];                  // O^T: row d=c*16+quad*4+r, col q=m16
#pragma unroll
    for (int c = 0; c < 4; ++c) { oA[c] = zero4; oB[c] = zero4; }
    float lsA = 0.f, lsB = 0.f;          // per-lane (q fixed) softmax denominators

    stage(0, 0);
    if (1 <= tB) stage(1, 1);
    int cur = 0;
    for (int t = 0; t <= tB; ++t) {
        int kt = t * 64;
        bool doA = (t <= tA);
        if (t < tB) asm volatile("s_waitcnt vmcnt(4)" ::: "memory");
        else        asm volatile("s_waitcnt vmcnt(0)" ::: "memory");
        asm volatile("s_barrier" ::: "memory");
        if (t + 2 <= tB) {
            int nxt = cur + 2; if (nxt >= 3) nxt -= 3;
            stage(t + 2, nxt);
        }

        const _Float16* kb = &KV[cur * 8192];
        const _Float16* vb = &KV[cur * 8192 + 4096];
        f16x8 bk[4][2];
#pragma unroll
        for (int s = 0; s < 4; ++s) {
            const _Float16* kr = kb + (s * 16 + m16) * 64;
            bk[s][0] = *(const f16x8*)(kr + cka);
            bk[s][1] = *(const f16x8*)(kr + ckb);
        }
        f16x4 av[4][4];                  // [c d-block][s key-chunk]
#pragma unroll
        for (int c = 0; c < 4; ++c) {
            const _Float16* vr = vb + (c * 16 + m16) * 64;
#pragma unroll
            for (int s = 0; s < 4; ++s)
                av[c][s] = *(const f16x4*)(vr + vco[s]);
        }

        // ---- body B (always) ----
        {
            f32x4 st[4];
#pragma unroll
            for (int s = 0; s < 4; ++s) {
                st[s] = MFMA16(bk[s][0], aqB0, zero4);
                st[s] = MFMA16(bk[s][1], aqB1, st[s]);
            }
            f16x4 pt[4];
#pragma unroll
            for (int s = 0; s < 4; ++s) {
#pragma unroll
                for (int r = 0; r < 4; ++r) {
                    int key = kt + s * 16 + quad * 4 + r;
                    float p = (key > qB) ? 0.0f : exp2f(st[s][r]);
                    lsB += p;
                    pt[s][r] = (_Float16)p;
                }
            }
#pragma unroll
            for (int c = 0; c < 4; ++c)
#pragma unroll
                for (int s = 0; s < 4; ++s)
                    oB[c] = MFMA16K16(av[c][s], pt[s], oB[c]);
        }
        // ---- body A (while t <= tA) ----
        if (doA) {
            f32x4 st[4];
#pragma unroll
            for (int s = 0; s < 4; ++s) {
                st[s] = MFMA16(bk[s][0], aqA0, zero4);
                st[s] = MFMA16(bk[s][1], aqA1, st[s]);
            }
            f16x4 pt[4];
#pragma unroll
            for (int s = 0; s < 4; ++s) {
#pragma unroll
                for (int r = 0; r < 4; ++r) {
                    int key = kt + s * 16 + quad * 4 + r;
                    float p = (key > qA) ? 0.0f : exp2f(st[s][r]);
                    lsA += p;
                    pt[s][r] = (_Float16)p;
                }
            }
#pragma unroll
            for (int c = 0; c < 4; ++c)
#pragma unroll
                for (int s = 0; s < 4; ++s)
                    oA[c] = MFMA16K16(av[c][s], pt[s], oA[c]);
        }
        cur = (cur == 2) ? 0 : cur + 1;
    }

    // epilogue: reduce lsum across quads (same q in 4 quads), normalize, store O^T
#pragma unroll
    for (int half = 0; half < 2; ++half) {
        f32x4* o = half ? oB : oA;
        float ls = half ? lsB : lsA;
        int qg = half ? (qbB + m16) : (qbA + m16);
        float rs = ls;
        rs += __shfl_xor(rs, 16);
        rs += __shfl_xor(rs, 32);
        float inv = 1.0f / rs;
        size_t rowoff = ((size_t)(b * SS) + qg) * HH + h * HDD;
#pragma unroll
        for (int c = 0; c < 4; ++c) {
            f16x4 ov;
#pragma unroll
            for (int r = 0; r < 4; ++r) ov[r] = (_Float16)(o[c][r] * inv);
            *(f16x4*)&Ctx[rowoff + c * 16 + quad * 4] = ov;
        }
    }
}

extern "C" void kernel_launch(void* const* d_in, const int* in_sizes, int n_in,
                              void* d_out, int out_size, void* d_ws, size_t ws_size,
                              hipStream_t stream) {
    const float* hs = (const float*)d_in[0];
    const float* Wq = (const float*)d_in[1];
    const float* bq = (const float*)d_in[2];
    const float* Wk = (const float*)d_in[3];
    const float* bk = (const float*)d_in[4];
    const float* Wv = (const float*)d_in[5];
    const float* bv = (const float*)d_in[6];
    const float* Wo = (const float*)d_in[7];
    const float* bo = (const float*)d_in[8];
    float* out = (float*)d_out;

    size_t off = 0;
    auto alloc = [&](size_t bytes) {
        void* p = (char*)d_ws + off;
        off += (bytes + 255) & ~(size_t)255;
        return p;
    };
    _Float16* Xh    = (_Float16*)alloc((size_t)MM * HH * 2);
    _Float16* WqkvT = (_Float16*)alloc((size_t)3 * HH * HH * 2);
    _Float16* WoT   = (_Float16*)alloc((size_t)HH * HH * 2);
    _Float16* Qh    = (_Float16*)alloc((size_t)BB * NHH * SS * HDD * 2);
    _Float16* Kh    = (_Float16*)alloc((size_t)BB * NHH * SS * HDD * 2);
    _Float16* Vt    = (_Float16*)alloc((size_t)BB * NHH * SS * HDD * 2);
    _Float16* Ctx   = (_Float16*)alloc((size_t)MM * HH * 2);

    cast4_kernel<<<(MM * HH / 4 + 255) / 256, 256, 0, stream>>>(hs, Xh, MM * HH / 4);
    transpose_kernel<<<dim3(16, 16, 4), 256, 0, stream>>>(Wq, Wk, Wv, Wo, WqkvT, WoT);
    gemm128_kernel<0><<<dim3(QKV_N / 128, MM / 128), 256, 0, stream>>>(
        Xh, WqkvT, bq, bk, bv, Qh, Kh, Vt, nullptr);
    attn_kernel<<<dim3(16, NHH, BB), 256, 0, stream>>>(Qh, Kh, Vt, Ctx);
    gemm128_kernel<1><<<dim3(HH / 128, MM / 128), 256, 0, stream>>>(
        Ctx, WoT, bo, bo, bo, nullptr, nullptr, nullptr, out);
}

// Round 13
// 191.874 us; speedup vs baseline: 1.2244x; 1.0196x over previous
//
#include <hip/hip_runtime.h>
#include <hip/hip_bf16.h>

// Problem constants
#define BB 2
#define SS 2048
#define HH 1024
#define NHH 16
#define HDD 64
#define MM (BB*SS)        // 4096
#define QKV_N (3*HH)      // 3072

typedef _Float16 f16x8 __attribute__((ext_vector_type(8)));
typedef _Float16 f16x4 __attribute__((ext_vector_type(4)));
typedef float f32x4 __attribute__((ext_vector_type(4)));

#define MFMA16(a,b,c)  __builtin_amdgcn_mfma_f32_16x16x32_f16((a),(b),(c),0,0,0)
#define MFMA16K16(a,b,c) __builtin_amdgcn_mfma_f32_16x16x16f16((a),(b),(c),0,0,0)

// async global->LDS 16B per lane; LDS dest = wave-uniform base + lane*16
__device__ __forceinline__ void gl2lds16(const _Float16* g, _Float16* l) {
    __builtin_amdgcn_global_load_lds(
        (const __attribute__((address_space(1))) void*)g,
        (__attribute__((address_space(3))) void*)l, 16, 0, 0);
}

// single-instruction exp2 WITH compiler hazard handling (raw asm broke TRANS-op waits)
__device__ __forceinline__ float fexp2(float x) { return __builtin_amdgcn_exp2f(x); }

// ---------------- prep: z<4 transpose-cast W -> Wt fp16; z==4 cast X -> fp16 ------------
// grid (16,16,5), block 256.
__global__ __launch_bounds__(256) void prep_kernel(
    const float* __restrict__ X,
    const float* __restrict__ W0, const float* __restrict__ W1,
    const float* __restrict__ W2, const float* __restrict__ W3,
    _Float16* __restrict__ Xh,
    _Float16* __restrict__ WqkvT, _Float16* __restrict__ WoT)
{
    __shared__ float t[64][65];
    int z = blockIdx.z;
    int tid = threadIdx.x;
    if (z == 4) {
        int base = (blockIdx.y * 16 + blockIdx.x) * 256 + tid;
        const float4* xin = (const float4*)X;
        f16x4* xout = (f16x4*)Xh;
#pragma unroll
        for (int i = 0; i < 16; ++i) {
            float4 v = xin[base + i * 65536];
            f16x4 hh = {(_Float16)v.x, (_Float16)v.y, (_Float16)v.z, (_Float16)v.w};
            xout[base + i * 65536] = hh;
        }
        return;
    }
    const float* src = (z == 0) ? W0 : (z == 1) ? W1 : (z == 2) ? W2 : W3;
    _Float16* dst = (z < 3) ? (WqkvT + (size_t)z * HH * HH) : WoT;
    int k0 = blockIdx.y * 64, n0 = blockIdx.x * 64;
#pragma unroll
    for (int p = 0; p < 4; ++p) {
        int row = p * 16 + (tid >> 4);
        int col4 = (tid & 15) * 4;
        float4 v = *(const float4*)&src[(size_t)(k0 + row) * HH + n0 + col4];
        t[row][col4 + 0] = v.x; t[row][col4 + 1] = v.y;
        t[row][col4 + 2] = v.z; t[row][col4 + 3] = v.w;
    }
    __syncthreads();
#pragma unroll
    for (int p = 0; p < 2; ++p) {
        int nc = p * 32 + (tid >> 3);
        int ch = tid & 7;
        f16x8 o;
#pragma unroll
        for (int j = 0; j < 8; ++j) o[j] = (_Float16)t[ch * 8 + j][nc];
        *(f16x8*)&dst[(size_t)(n0 + nc) * HH + k0 + ch * 8] = o;
    }
}

// ---------------- MFMA GEMM 128x128 tile, 3-stage pipeline, raw barrier ----------------
template<int MODE>
__global__ __launch_bounds__(256) void gemm128_kernel(
    const _Float16* __restrict__ A, const _Float16* __restrict__ Bt,
    const float* __restrict__ bias0, const float* __restrict__ bias1, const float* __restrict__ bias2,
    _Float16* __restrict__ Qh, _Float16* __restrict__ Kh, _Float16* __restrict__ Vt,
    float* __restrict__ Out)
{
    const int K = HH;
    const int NT = K / 32;
    __shared__ _Float16 smem[24576];          // 49152 B: 3-stage bufs U epilogue tile 128x132

    int row0 = blockIdx.y * 128, n0 = blockIdx.x * 128;
    int tid = threadIdx.x;
    int w = tid >> 6, l = tid & 63, m16 = l & 15, quad = l >> 4;
    int wm = w >> 1, wn = w & 1;

    int srow = w * 32 + (l >> 2);
    int sch = (l & 3) ^ ((l >> 2) & 3) ^ ((l >> 4) & 3);
    const _Float16* aptr = A + (size_t)(row0 + srow) * K + sch * 8;
    const _Float16* bptr = Bt + (size_t)(n0 + srow) * K + sch * 8;

    int gsw = (m16 & 3) ^ ((m16 >> 2) & 3);
    int acol = (quad ^ gsw) * 8;

    f32x4 zero4 = {0.f, 0.f, 0.f, 0.f};
    f32x4 acc[4][4];
#pragma unroll
    for (int i = 0; i < 4; ++i)
#pragma unroll
        for (int j = 0; j < 4; ++j) acc[i][j] = zero4;

    auto stage = [&](int t, int s) {
        int k0 = t * 32;
        int ao = s * 4096 + (w * 32) * 32;
        int bo = 12288 + s * 4096 + (w * 32) * 32;
        gl2lds16(aptr + k0, smem + ao);
        gl2lds16(aptr + (size_t)16 * K + k0, smem + ao + 16 * 32);
        gl2lds16(bptr + k0, smem + bo);
        gl2lds16(bptr + (size_t)16 * K + k0, smem + bo + 16 * 32);
    };

    stage(0, 0);
    stage(1, 1);
    int cur = 0;
    for (int t = 0; t < NT; ++t) {
        if (t < NT - 1) asm volatile("s_waitcnt vmcnt(4)" ::: "memory");
        else            asm volatile("s_waitcnt vmcnt(0)" ::: "memory");
        asm volatile("s_barrier" ::: "memory");
        if (t + 2 < NT) {
            int nxt = cur + 2; if (nxt >= 3) nxt -= 3;
            stage(t + 2, nxt);
        }
        const _Float16* Asr = smem + cur * 4096;
        const _Float16* Bsr = smem + 12288 + cur * 4096;
        f16x8 af[4], bf[4];
#pragma unroll
        for (int i = 0; i < 4; ++i)
            af[i] = *(const f16x8*)&Asr[(wm * 64 + i * 16 + m16) * 32 + acol];
#pragma unroll
        for (int j = 0; j < 4; ++j)
            bf[j] = *(const f16x8*)&Bsr[(wn * 64 + j * 16 + m16) * 32 + acol];
#pragma unroll
        for (int i = 0; i < 4; ++i)
#pragma unroll
            for (int j = 0; j < 4; ++j)
                acc[i][j] = MFMA16(af[i], bf[j], acc[i][j]);
        cur = (cur == 2) ? 0 : cur + 1;
    }

    if (MODE == 1) {
#pragma unroll
        for (int j = 0; j < 4; ++j) {
            int n = n0 + wn * 64 + j * 16 + m16;
            float bi = bias0[n];
#pragma unroll
            for (int i = 0; i < 4; ++i)
#pragma unroll
                for (int r = 0; r < 4; ++r) {
                    int mg = row0 + wm * 64 + i * 16 + quad * 4 + r;
                    Out[(size_t)mg * HH + n] = acc[i][j][r] + bi;
                }
        }
        return;
    }

    // ---- MODE 0 epilogue: bias (+scale for Q), LDS bounce, coalesced stores ----
    int which = n0 >> 10;                     // 0=Q 1=K 2=V (block is pure)
    const float* bias = (which == 0) ? bias0 : (which == 1) ? bias1 : bias2;
    __syncthreads();
#pragma unroll
    for (int j = 0; j < 4; ++j) {
        int n_local = wn * 64 + j * 16 + m16;
        float bi = bias[(n0 + n_local) & 1023];
#pragma unroll
        for (int i = 0; i < 4; ++i)
#pragma unroll
            for (int r = 0; r < 4; ++r) {
                int m_local = wm * 64 + i * 16 + quad * 4 + r;
                float v = acc[i][j][r] + bi;
                if (which == 0) v *= 0.18033688011112042f;  // (1/sqrt(64))*log2(e)
                if (which == 2) smem[n_local * 132 + m_local] = (_Float16)v;   // transposed
                else            smem[m_local * 132 + n_local] = (_Float16)v;
            }
    }
    __syncthreads();

    int b = row0 >> 11, s0 = row0 & 2047;
    if (which == 2) {
#pragma unroll
        for (int p = 0; p < 8; ++p) {
            int n_local = p * 16 + (tid >> 4);
            int schunk = tid & 15;
            f16x8 v = *(const f16x8*)&smem[n_local * 132 + schunk * 8];
            int nw = (n0 + n_local) & 1023;
            int hh = nw >> 6, d = nw & 63;
            *(f16x8*)&Vt[((size_t)(b * NHH + hh) * HDD + d) * SS + s0 + schunk * 8] = v;
        }
    } else {
        _Float16* dst = (which == 0) ? Qh : Kh;
        int hh0 = (n0 & 1023) >> 6;
#pragma unroll
        for (int p = 0; p < 8; ++p) {
            int m_local = p * 16 + (tid >> 4);
            int seg = tid & 15;
            f16x8 v = *(const f16x8*)&smem[m_local * 132 + seg * 8];
            int hh = hh0 + (seg >> 3), d = (seg & 7) * 8;
            *(f16x8*)&dst[((size_t)(b * NHH + hh) * SS + s0 + m_local) * HDD + d] = v;
        }
    }
}

// ---------------- Flash attention: S^T formulation, mask-hoisted, MFMA-lsum --------------
// grid (16, NH, B), block 256; paired q-tiles tA=bx, tB=31-bx; 3-stage K/V staging.
// Only the diagonal tile runs the masked body; softmax denominator via all-ones MFMA.
__global__ __launch_bounds__(256, 2) void attn_kernel(
    const _Float16* __restrict__ Qh, const _Float16* __restrict__ Kh,
    const _Float16* __restrict__ Vt, _Float16* __restrict__ Ctx)
{
    __shared__ _Float16 KV[3 * 8192];     // 49152 B, 3-stage K+V

    int tid = threadIdx.x;
    int w = tid >> 6, l = tid & 63;
    int m16 = l & 15, quad = l >> 4;
    int b = blockIdx.z, h = blockIdx.y;
    int tA = blockIdx.x, tB = 31 - tA;

    const _Float16* Q = Qh + (size_t)(b * NHH + h) * SS * HDD;
    const _Float16* K = Kh + (size_t)(b * NHH + h) * SS * HDD;
    const _Float16* V = Vt + (size_t)(b * NHH + h) * HDD * SS;

    int qbA = tA * 64 + w * 16, qbB = tB * 64 + w * 16;
    int qA = qbA + m16, qB = qbB + m16;          // this lane's q row (S^T: q = lane&15)
    f16x8 aqA0 = *(const f16x8*)(Q + (size_t)qA * HDD + quad * 8);
    f16x8 aqA1 = *(const f16x8*)(Q + (size_t)qA * HDD + 32 + quad * 8);
    f16x8 aqB0 = *(const f16x8*)(Q + (size_t)qB * HDD + quad * 8);
    f16x8 aqB1 = *(const f16x8*)(Q + (size_t)qB * HDD + 32 + quad * 8);

    // staging: wave w covers rows [w*16, w*16+16), two 8-row instrs per matrix
    int srow = w * 16 + (l >> 3);
    int sch = (l & 7) ^ (l >> 3);
    const _Float16* kg = K + (size_t)srow * HDD + sch * 8;
    const _Float16* vg = V + (size_t)srow * SS + sch * 8;

    auto stage = [&](int t, int s) {
        int kt = t * 64;
        _Float16* kb = &KV[s * 8192];
        _Float16* vb = &KV[s * 8192 + 4096];
        gl2lds16(kg + (size_t)kt * HDD, kb + (w * 16) * 64);
        gl2lds16(kg + (size_t)(kt + 8) * HDD, kb + (w * 16 + 8) * 64);
        gl2lds16(vg + kt, vb + (w * 16) * 64);
        gl2lds16(vg + (size_t)8 * SS + kt, vb + (w * 16 + 8) * 64);
    };

    int swz = m16 & 7;
    int cka = (quad ^ swz) * 8;          // K-frag d-chunk 0..31
    int ckb = ((quad + 4) ^ swz) * 8;    // K-frag d-chunk 32..63
    int vco[4];
#pragma unroll
    for (int s = 0; s < 4; ++s)
        vco[s] = (((s * 2 + (quad >> 1)) ^ swz) * 8) + (quad & 1) * 4;

    f32x4 zero4 = {0.f, 0.f, 0.f, 0.f};
    const f16x4 ones4 = {(_Float16)1.f, (_Float16)1.f, (_Float16)1.f, (_Float16)1.f};
    f32x4 oA[4], oB[4];                  // O^T: row d=c*16+quad*4+r, col q=m16
#pragma unroll
    for (int c = 0; c < 4; ++c) { oA[c] = zero4; oB[c] = zero4; }
    f32x4 laccA = zero4, laccB = zero4;  // softmax denominators (all rows identical)

    stage(0, 0);
    if (1 <= tB) stage(1, 1);
    int cur = 0;
    for (int t = 0; t <= tB; ++t) {
        int kt = t * 64;
        if (t < tB) asm volatile("s_waitcnt vmcnt(4)" ::: "memory");
        else        asm volatile("s_waitcnt vmcnt(0)" ::: "memory");
        asm volatile("s_barrier" ::: "memory");
        if (t + 2 <= tB) {
            int nxt = cur + 2; if (nxt >= 3) nxt -= 3;
            stage(t + 2, nxt);
        }

        const _Float16* kb = &KV[cur * 8192];
        const _Float16* vb = &KV[cur * 8192 + 4096];
        f16x8 bk[4][2];
#pragma unroll
        for (int s = 0; s < 4; ++s) {
            const _Float16* kr = kb + (s * 16 + m16) * 64;
            bk[s][0] = *(const f16x8*)(kr + cka);
            bk[s][1] = *(const f16x8*)(kr + ckb);
        }
        f16x4 av[4][4];                  // [c d-block][s key-chunk]
#pragma unroll
        for (int c = 0; c < 4; ++c) {
            const _Float16* vr = vb + (c * 16 + m16) * 64;
#pragma unroll
            for (int s = 0; s < 4; ++s)
                av[c][s] = *(const f16x4*)(vr + vco[s]);
        }

        auto body = [&](const f16x8& q0, const f16x8& q1, int qlane,
                        f32x4* o, f32x4& lacc, bool masked) {
            f32x4 st[4];
#pragma unroll
            for (int s = 0; s < 4; ++s) {
                st[s] = MFMA16(bk[s][0], q0, zero4);
                st[s] = MFMA16(bk[s][1], q1, st[s]);
            }
            f16x4 pt[4];
#pragma unroll
            for (int s = 0; s < 4; ++s) {
#pragma unroll
                for (int r = 0; r < 4; ++r) {
                    float p = fexp2(st[s][r]);
                    if (masked) {
                        int key = kt + s * 16 + quad * 4 + r;
                        if (key > qlane) p = 0.f;
                    }
                    pt[s][r] = (_Float16)p;
                }
                lacc = MFMA16K16(ones4, pt[s], lacc);
            }
#pragma unroll
            for (int c = 0; c < 4; ++c)
#pragma unroll
                for (int s = 0; s < 4; ++s)
                    o[c] = MFMA16K16(av[c][s], pt[s], o[c]);
        };

        if (t == tB) body(aqB0, aqB1, qB, oB, laccB, true);
        else         body(aqB0, aqB1, qB, oB, laccB, false);
        if (t == tA)      body(aqA0, aqA1, qA, oA, laccA, true);
        else if (t < tA)  body(aqA0, aqA1, qA, oA, laccA, false);

        cur = (cur == 2) ? 0 : cur + 1;
    }

    // epilogue: normalize (denominator identical across rows/quads for a given q), store O^T
#pragma unroll
    for (int half = 0; half < 2; ++half) {
        f32x4* o = half ? oB : oA;
        float rs = half ? laccB[0] : laccA[0];
        int qg = half ? qB : qA;
        float inv = 1.0f / rs;
        size_t rowoff = ((size_t)(b * SS) + qg) * HH + h * HDD;
#pragma unroll
        for (int c = 0; c < 4; ++c) {
            f16x4 ov;
#pragma unroll
            for (int r = 0; r < 4; ++r) ov[r] = (_Float16)(o[c][r] * inv);
            *(f16x4*)&Ctx[rowoff + c * 16 + quad * 4] = ov;
        }
    }
}

extern "C" void kernel_launch(void* const* d_in, const int* in_sizes, int n_in,
                              void* d_out, int out_size, void* d_ws, size_t ws_size,
                              hipStream_t stream) {
    const float* hs = (const float*)d_in[0];
    const float* Wq = (const float*)d_in[1];
    const float* bq = (const float*)d_in[2];
    const float* Wk = (const float*)d_in[3];
    const float* bk = (const float*)d_in[4];
    const float* Wv = (const float*)d_in[5];
    const float* bv = (const float*)d_in[6];
    const float* Wo = (const float*)d_in[7];
    const float* bo = (const float*)d_in[8];
    float* out = (float*)d_out;

    size_t off = 0;
    auto alloc = [&](size_t bytes) {
        void* p = (char*)d_ws + off;
        off += (bytes + 255) & ~(size_t)255;
        return p;
    };
    _Float16* Xh    = (_Float16*)alloc((size_t)MM * HH * 2);
    _Float16* WqkvT = (_Float16*)alloc((size_t)3 * HH * HH * 2);
    _Float16* WoT   = (_Float16*)alloc((size_t)HH * HH * 2);
    _Float16* Qh    = (_Float16*)alloc((size_t)BB * NHH * SS * HDD * 2);
    _Float16* Kh    = (_Float16*)alloc((size_t)BB * NHH * SS * HDD * 2);
    _Float16* Vt    = (_Float16*)alloc((size_t)BB * NHH * SS * HDD * 2);
    _Float16* Ctx   = (_Float16*)alloc((size_t)MM * HH * 2);

    prep_kernel<<<dim3(16, 16, 5), 256, 0, stream>>>(
        hs, Wq, Wk, Wv, Wo, Xh, WqkvT, WoT);
    gemm128_kernel<0><<<dim3(QKV_N / 128, MM / 128), 256, 0, stream>>>(
        Xh, WqkvT, bq, bk, bv, Qh, Kh, Vt, nullptr);
    attn_kernel<<<dim3(16, NHH, BB), 256, 0, stream>>>(Qh, Kh, Vt, Ctx);
    gemm128_kernel<1><<<dim3(HH / 128, MM / 128), 256, 0, stream>>>(
        Ctx, WoT, bo, bo, bo, nullptr, nullptr, nullptr, out);
}